// Round 1
// 943.437 us; speedup vs baseline: 1.5911x; 1.5911x over previous
//
#include <hip/hip_runtime.h>

#define NN 50000
#define EE 400000

// chunked-scan params
#define CH_H 16384            // 64 KB LDS (int/float)
#define NCH_H 4               // 4*16384 >= 50000
#define ESL_H 2
#define EPS_H (EE/ESL_H)      // 200000
#define I4_H (EPS_H/4)        // 50000 int4

#define ESL_C 4
#define EPS_C (EE/ESL_C)      // 100000
#define I4_C (EPS_C/4)        // 25000 int4

#define CH_D 4096             // float4 chunk -> 64 KB LDS
#define NCH_D 13              // 13*4096 >= 50000
#define ESL_D 2
#define EPS_D (EE/ESL_D)      // 200000
#define I4_D (EPS_D/4)        // 50000 int4

#define NZ 261                // k_y_big row-chunks (261*192 = 50112 >= 50000)
#define ZROWS 192             // 3 tiles of 64

#define VCH 96                // k_v f-chunk (8 chunks cover 768)

// relation tables: src(r) = r/4
__constant__ int DSTT[20]     = {1,2,3,4, 2,0,3,4, 0,1,3,4, 0,1,2,4, 0,2,3,1};
__constant__ int KIDX[20]     = {0,0,0,0, 1,0,1,1, 1,1,2,2, 2,2,2,3, 3,3,3,3};
__constant__ int DSTREL[5][4] = {{5,8,12,16},{0,9,13,19},{1,4,14,17},{2,6,10,18},{3,7,11,15}};
__constant__ int FEATS[5]     = {5, 16, 21, 768, 768};

// ---- workspace arena (4B element offsets), phase-aliased ----
#define OFF_HIST 0           // 4 x 1M int   (hist -> norms)
#define OFF_CRAW 0           // 4 x 1M float (craw -> cS)
#define OFF_CC4  0           // 4M float     (cc -> dacc)
#define OFF_C    4000000     // 1M (cS -> cc)
#define OFF_ND   5000000     // 1M (norms -> cc/craw)
#define OFF_PART 0           // 1044 slots * 6144 = 6,414,336 (y_big -> red_y)
#define OFF_YS   6500000     // 61440 (y_small -> red_y)
#define OFF_S    6600000     // 64    (cS -> k_m)
#define OFF_V    6700000     // 2560  (atomically accumulated; zeroed at start; outside dacc alias)
#define OFF_NS   7000000     // 1M    (norms -> y)
#define OFF_DACC 8000000     // 2 x 4M (dacc -> y)
#define DSLICE   4000000
#define OFF_Y    8000000     // 61440 (red_y -> v; dacc dead)
#define OFF_MP   8110000     // 2560  (k_m writes fully after dacc dead)
#define TOTAL_ELEMS 16000000

static __device__ __forceinline__ void fma4(float4& a, const float4& x, float w) {
    a.x += w * x.x; a.y += w * x.y; a.z += w * x.z; a.w += w * x.w;
}

// z = arr*20 + r; arr 0: src keys (dego), 1: dst keys (degi)
__global__ __launch_bounds__(1024) void k_hist(const int* __restrict__ edges, int* __restrict__ hist_part) {
    __shared__ int h[CH_H];
    const int slice = blockIdx.x, chunk = blockIdx.y;
    const int r = blockIdx.z % 20, arr = blockIdx.z / 20;
    for (int i = threadIdx.x; i < CH_H; i += 1024) h[i] = 0;
    __syncthreads();
    const int4* key = (const int4*)(edges + (size_t)(r*2 + arr)*EE + slice*EPS_H);
    const int base = chunk * CH_H;
    for (int i = threadIdx.x; i < I4_H; i += 1024) {
        int4 k4 = key[i];
        unsigned a = (unsigned)(k4.x - base), b = (unsigned)(k4.y - base);
        unsigned c = (unsigned)(k4.z - base), d = (unsigned)(k4.w - base);
        if (a < CH_H) atomicAdd(&h[a], 1);
        if (b < CH_H) atomicAdd(&h[b], 1);
        if (c < CH_H) atomicAdd(&h[c], 1);
        if (d < CH_H) atomicAdd(&h[d], 1);
    }
    __syncthreads();
    int* outp = hist_part + (arr*ESL_H + slice)*1000000 + r*NN;
    for (int i = threadIdx.x; i < CH_H; i += 1024) {
        int u = base + i;
        if (u < NN) outp[u] = h[i];
    }
}

__global__ __launch_bounds__(256) void k_norms(const int* __restrict__ hist_part,
                                               float* __restrict__ ns, float* __restrict__ nd) {
    int r = blockIdx.y;
    int u = blockIdx.x * 256 + threadIdx.x;
    if (u >= NN) return;
    int idx = r*NN + u;
    float dop = (float)(hist_part[idx] + hist_part[1000000 + idx]);
    float dip = (float)(hist_part[2000000 + idx] + hist_part[3000000 + idx]);
    if (dop < 1.f) dop = 1.f;
    if (dip < 1.f) dip = 1.f;
    ns[idx] = 1.0f / sqrtf(dop);
    nd[idx] = 1.0f / sqrtf(dip);
}

// craw[s] = sum_{e:src=s} nd[dst]
__global__ __launch_bounds__(1024) void k_craw(const int* __restrict__ edges,
                                               const float* __restrict__ nd, float* __restrict__ craw_part) {
    __shared__ float h[CH_H];
    const int slice = blockIdx.x, chunk = blockIdx.y, r = blockIdx.z;
    for (int i = threadIdx.x; i < CH_H; i += 1024) h[i] = 0.f;
    __syncthreads();
    const int4* s4 = (const int4*)(edges + (size_t)(r*2)*EE + slice*EPS_C);
    const int4* d4 = (const int4*)(edges + (size_t)(r*2+1)*EE + slice*EPS_C);
    const float* ndr = nd + r*NN;
    const int base = chunk * CH_H;
    for (int i = threadIdx.x; i < I4_C; i += 1024) {
        int4 s = s4[i];
        int4 d = d4[i];
        unsigned a = (unsigned)(s.x - base), b = (unsigned)(s.y - base);
        unsigned c = (unsigned)(s.z - base), e = (unsigned)(s.w - base);
        if (a < CH_H) atomicAdd(&h[a], ndr[d.x]);
        if (b < CH_H) atomicAdd(&h[b], ndr[d.y]);
        if (c < CH_H) atomicAdd(&h[c], ndr[d.z]);
        if (e < CH_H) atomicAdd(&h[e], ndr[d.w]);
    }
    __syncthreads();
    float* outp = craw_part + slice*1000000 + r*NN;
    for (int i = threadIdx.x; i < CH_H; i += 1024) {
        int u = base + i;
        if (u < NN) outp[u] = h[i];
    }
}

__global__ __launch_bounds__(256) void k_cS(const float* __restrict__ craw_part, const float* __restrict__ ns,
                                            float* __restrict__ c, float* __restrict__ S) {
    int r = blockIdx.y;
    int u = blockIdx.x * 256 + threadIdx.x;
    float val = 0.f;
    if (u < NN) {
        int idx = r*NN + u;
        val = ns[idx] * (craw_part[idx] + craw_part[1000000 + idx]
                       + craw_part[2000000 + idx] + craw_part[3000000 + idx]);
        c[idx] = val;
    }
    for (int off = 32; off > 0; off >>= 1) val += __shfl_down(val, off, 64);
    __shared__ float red[4];
    if ((threadIdx.x & 63) == 0) red[threadIdx.x >> 6] = val;
    __syncthreads();
    if (threadIdx.x == 0) atomicAdd(&S[r], red[0] + red[1] + red[2] + red[3]);
}

// cc4[r1][u] = { c[4*dst(r1)+j][u] * nd[r1][u] : j=0..3 }
__global__ __launch_bounds__(256) void k_cc(const float* __restrict__ c, const float* __restrict__ nd,
                                            float* __restrict__ cc4) {
    int r1 = blockIdx.y;
    int u = blockIdx.x * 256 + threadIdx.x;
    if (u >= NN) return;
    float ndv = nd[r1*NN + u];
    int d1 = DSTT[r1];
    float4 w;
    w.x = c[(4*d1+0)*NN + u] * ndv;
    w.y = c[(4*d1+1)*NN + u] * ndv;
    w.z = c[(4*d1+2)*NN + u] * ndv;
    w.w = c[(4*d1+3)*NN + u] * ndv;
    *(float4*)(cc4 + (size_t)(r1*NN + u) * 4) = w;
}

// dacc[p][s] = sum_{e in r1, src=s} cc_j[dst]
__global__ __launch_bounds__(1024) void k_dacc(const int* __restrict__ edges,
                                               const float* __restrict__ cc4, float* __restrict__ dacc_part) {
    __shared__ float h4[CH_D * 4];
    const int slice = blockIdx.x, chunk = blockIdx.y, r = blockIdx.z;
    for (int i = threadIdx.x; i < CH_D * 4; i += 1024) h4[i] = 0.f;
    __syncthreads();
    const int4* s4 = (const int4*)(edges + (size_t)(r*2)*EE + slice*EPS_D);
    const int4* d4 = (const int4*)(edges + (size_t)(r*2+1)*EE + slice*EPS_D);
    const float* ccr = cc4 + (size_t)r*NN*4;
    const int base = chunk * CH_D;
    for (int i = threadIdx.x; i < I4_D; i += 1024) {
        int4 s = s4[i];
        int4 d = d4[i];
        unsigned a = (unsigned)(s.x - base), b = (unsigned)(s.y - base);
        unsigned c = (unsigned)(s.z - base), e = (unsigned)(s.w - base);
        if (a < CH_D) {
            const float4 w = *(const float4*)(ccr + (size_t)d.x * 4);
            atomicAdd(&h4[a*4+0], w.x); atomicAdd(&h4[a*4+1], w.y);
            atomicAdd(&h4[a*4+2], w.z); atomicAdd(&h4[a*4+3], w.w);
        }
        if (b < CH_D) {
            const float4 w = *(const float4*)(ccr + (size_t)d.y * 4);
            atomicAdd(&h4[b*4+0], w.x); atomicAdd(&h4[b*4+1], w.y);
            atomicAdd(&h4[b*4+2], w.z); atomicAdd(&h4[b*4+3], w.w);
        }
        if (c < CH_D) {
            const float4 w = *(const float4*)(ccr + (size_t)d.z * 4);
            atomicAdd(&h4[c*4+0], w.x); atomicAdd(&h4[c*4+1], w.y);
            atomicAdd(&h4[c*4+2], w.z); atomicAdd(&h4[c*4+3], w.w);
        }
        if (e < CH_D) {
            const float4 w = *(const float4*)(ccr + (size_t)d.w * 4);
            atomicAdd(&h4[e*4+0], w.x); atomicAdd(&h4[e*4+1], w.y);
            atomicAdd(&h4[e*4+2], w.z); atomicAdd(&h4[e*4+3], w.w);
        }
    }
    __syncthreads();
    const int d1 = DSTT[r], kk = KIDX[r];
    float* op = dacc_part + slice * DSLICE;
#pragma unroll
    for (int j = 0; j < 4; ++j) {
        int p = 4*(4*d1 + j) + kk;
        float* pj = op + (size_t)p*NN;
        for (int i = threadIdx.x; i < CH_D; i += 1024) {
            int u = base + i;
            if (u < NN) pj[u] = h4[i*4 + j];
        }
    }
}

// y partials, 768-wide src ntypes. Block = (row-chunk z, half, group); 8 q's; own slot, no atomics.
__global__ __launch_bounds__(192) void k_y_big(const float* __restrict__ xn, const float* __restrict__ xp,
        const float* __restrict__ ns, const float* __restrict__ dacc, float* __restrict__ partial) {
    __shared__ float wlds[64 * 8];
    const int tid = threadIdx.x;
    const int z = blockIdx.x, half = blockIdx.y, group = blockIdx.z;
    const int s1 = 3 + group;
    const float* x = (group == 0) ? xn : xp;
    const int c0 = tid * 4;
    float4 acc[8];
#pragma unroll
    for (int q = 0; q < 8; ++q) acc[q] = make_float4(0.f, 0.f, 0.f, 0.f);

    for (int t = 0; t < 3; ++t) {
        const int u0 = z * ZROWS + t * 64;
        __syncthreads();
        for (int tt = tid; tt < 512; tt += 192) {
            int ql = tt >> 6, ri = tt & 63;
            int i = half*2 + (ql >> 2), j = ql & 3;
            int r1 = 4*s1 + i;
            int p = 4*(4*DSTT[r1] + j) + KIDX[r1];
            int u = u0 + ri;
            float w = 0.f;
            if (u < NN) {
                int idx = p*NN + u;
                w = ns[r1*NN + u] * (dacc[idx] + dacc[DSLICE + idx]);
            }
            wlds[ri*8 + ql] = w;
        }
        __syncthreads();
        const int rmax = (NN - u0 < 64) ? (NN - u0) : 64;
#pragma unroll 4
        for (int ri = 0; ri < rmax; ++ri) {
            const float4 xv = *(const float4*)(x + (size_t)(u0 + ri) * 768 + c0);
            const float4 wa = *(const float4*)(wlds + ri * 8);
            const float4 wb = *(const float4*)(wlds + ri * 8 + 4);
            fma4(acc[0], xv, wa.x); fma4(acc[1], xv, wa.y);
            fma4(acc[2], xv, wa.z); fma4(acc[3], xv, wa.w);
            fma4(acc[4], xv, wb.x); fma4(acc[5], xv, wb.y);
            fma4(acc[6], xv, wb.z); fma4(acc[7], xv, wb.w);
        }
    }
    float* pslot = partial + (size_t)(z*4 + group*2 + half) * 6144;
#pragma unroll
    for (int ql = 0; ql < 8; ++ql)
        *(float4*)(pslot + ql * 768 + c0) = acc[ql];
}

// small-F: per (q, u-chunk) block; dacc read once; wave-shuffle + LDS reduce; few global atomics
template<int F>
__global__ __launch_bounds__(256) void k_y_small(const float* __restrict__ x,
        const float* __restrict__ ns, const float* __restrict__ dacc,
        float* __restrict__ ys, int s1) {
    const int q = blockIdx.x;
    const int i = q >> 2, j = q & 3;
    const int r1 = 4*s1 + i;
    const int p = 4*(4*DSTT[r1] + j) + KIDX[r1];
    const float* nsp = ns + r1*NN;
    const float* d0 = dacc + (size_t)p*NN;
    const float* d1 = d0 + DSLICE;
    float acc[F];
#pragma unroll
    for (int f = 0; f < F; ++f) acc[f] = 0.f;
    const int u0 = blockIdx.y * 6250;
    for (int u = u0 + threadIdx.x; u < u0 + 6250; u += 256) {
        float w = nsp[u] * (d0[u] + d1[u]);
        const float* xr = x + (size_t)u * F;
#pragma unroll
        for (int f = 0; f < F; ++f) acc[f] += w * xr[f];
    }
#pragma unroll
    for (int f = 0; f < F; ++f)
        for (int off = 32; off > 0; off >>= 1) acc[f] += __shfl_down(acc[f], off, 64);
    __shared__ float red[F];
    if (threadIdx.x < F) red[threadIdx.x] = 0.f;
    __syncthreads();
    if ((threadIdx.x & 63) == 0) {
#pragma unroll
        for (int f = 0; f < F; ++f) atomicAdd(&red[f], acc[f]);
    }
    __syncthreads();
    if (threadIdx.x < F) atomicAdd(&ys[p*768 + threadIdx.x], red[threadIdx.x]);
}

__global__ __launch_bounds__(768) void k_red_y(const float* __restrict__ partial,
                                               const float* __restrict__ ys, float* __restrict__ y) {
    const int p = blockIdx.x;
    const int f = threadIdx.x;
    const int r2 = p >> 2, k = p & 3;
    const int r1 = DSTREL[r2 >> 2][k];
    const int s1 = r1 >> 2;
    float s = ys[p*768 + f];
    if (s1 >= 3) {
        const int group = s1 - 3;
        const int i = r1 & 3;
        const int half = i >> 1;
        const int ql = (i & 1) * 4 + (r2 & 3);
        const float* base = partial + (size_t)(group*2 + half) * 6144 + ql * 768 + f;
        for (int z = 0; z < NZ; ++z) s += base[(size_t)z * 4 * 6144];
    }
    y[p*768 + f] = s;
}

// v[r2][c] += sum over this block's f-chunk of y[4*r2+k][f] * W1[r1(k)][f][c]
// grid (20, 4, 8): r2 x k x f-chunk; latency hidden by 640 concurrent blocks.
__global__ __launch_bounds__(128) void k_v(const float* __restrict__ y,
        const float* __restrict__ W1s, const float* __restrict__ W1f, const float* __restrict__ W1m,
        const float* __restrict__ W1n, const float* __restrict__ W1p, float* __restrict__ v) {
    const int r2 = blockIdx.x;
    const int k  = blockIdx.y;
    const int fc = blockIdx.z;
    const int c  = threadIdx.x;
    const int r1 = DSTREL[r2 >> 2][k];
    const int s1 = r1 >> 2;
    const int F  = FEATS[s1];
    const int f0 = fc * VCH;
    if (f0 >= F) return;
    const int f1 = (f0 + VCH < F) ? (f0 + VCH) : F;
    const float* W1 = (s1 == 0 ? W1s : s1 == 1 ? W1f : s1 == 2 ? W1m : s1 == 3 ? W1n : W1p)
                      + (size_t)(r1 & 3) * F * 128;
    const float* yp = y + (r2*4 + k) * 768;
    float sum = 0.f;
#pragma unroll 4
    for (int f = f0; f < f1; ++f) sum += yp[f] * W1[(size_t)f * 128 + c];
    atomicAdd(&v[r2 * 128 + c], sum);
}

// mpart[r2][c] = sum_k (v[r2][k] + S[r2]*bsum1_{src(r2)}[k]) * W2[r2][k][c]
__global__ __launch_bounds__(128) void k_m(const float* __restrict__ v, const float* __restrict__ S,
        const float* __restrict__ b1, const float* __restrict__ W2, float* __restrict__ mpart) {
    int r2 = blockIdx.x;
    int c = threadIdx.x;
    __shared__ float vp[128];
    int s2 = r2 >> 2;
    float b = b1[DSTREL[s2][0]*128 + c] + b1[DSTREL[s2][1]*128 + c]
            + b1[DSTREL[s2][2]*128 + c] + b1[DSTREL[s2][3]*128 + c];
    vp[c] = v[r2*128 + c] + S[r2] * b;
    __syncthreads();
    const float* W2r = W2 + r2 * 16384;
    float sum = 0.f;
    for (int k = 0; k < 128; ++k) sum += vp[k] * W2r[k * 128 + c];
    mpart[r2 * 128 + c] = sum;
}

__global__ __launch_bounds__(128) void k_out(const float* __restrict__ mpart, const float* __restrict__ b2,
        const float* __restrict__ Wfc, const float* __restrict__ bfc, float* __restrict__ out) {
    int c = threadIdx.x;
    __shared__ float ml[128];
    float bs = 0.f, ms = 0.f;
    for (int r2 = 0; r2 < 20; ++r2) { bs += b2[r2 * 128 + c]; ms += mpart[r2 * 128 + c]; }
    float m = (ms + (float)NN * bs) * (1.0f / (5.0f * (float)NN));
    out[c] = m;
    ml[c] = m;
    __syncthreads();
    if (c < 10) {
        float o = bfc[c];
        for (int k = 0; k < 128; ++k) o += ml[k] * Wfc[k * 10 + c];
        out[128 + c] = o;
    }
}

extern "C" void kernel_launch(void* const* d_in, const int* in_sizes, int n_in,
                              void* d_out, int out_size, void* d_ws, size_t ws_size,
                              hipStream_t stream) {
    (void)in_sizes; (void)n_in; (void)out_size;
    const float* xs  = (const float*)d_in[0];
    const float* xf  = (const float*)d_in[1];
    const float* xm  = (const float*)d_in[2];
    const float* xn  = (const float*)d_in[3];
    const float* xp  = (const float*)d_in[4];
    const float* W1s = (const float*)d_in[5];
    const float* W1f = (const float*)d_in[6];
    const float* W1m = (const float*)d_in[7];
    const float* W1n = (const float*)d_in[8];
    const float* W1p = (const float*)d_in[9];
    const float* b1  = (const float*)d_in[10];
    const float* W2  = (const float*)d_in[11];
    const float* b2  = (const float*)d_in[12];
    const float* Wfc = (const float*)d_in[13];
    const float* bfc = (const float*)d_in[14];
    const int* edges = (const int*)d_in[15];
    float* ws = (float*)d_ws;
    int* wsi = (int*)d_ws;
    float* out = (float*)d_out;
    if (ws_size < (size_t)TOTAL_ELEMS * 4) return;

    dim3 t256(256), nb(196, 20);

    // zero YS (6,500,000..6,561,440) and S (6,600,000..6,600,064) in one memset
    hipMemsetAsync(ws + OFF_YS, 0, (size_t)(OFF_S + 64 - OFF_YS) * 4, stream);
    // zero V accumulator (now at 6,700,000, outside the dacc alias region)
    hipMemsetAsync(ws + OFF_V, 0, 2560 * 4, stream);

    k_hist<<<dim3(ESL_H, NCH_H, 40), dim3(1024), 0, stream>>>(edges, wsi + OFF_HIST);
    k_norms<<<nb, t256, 0, stream>>>(wsi + OFF_HIST, ws + OFF_NS, ws + OFF_ND);
    k_craw<<<dim3(ESL_C, NCH_H, 20), dim3(1024), 0, stream>>>(edges, ws + OFF_ND, ws + OFF_CRAW);
    k_cS<<<nb, t256, 0, stream>>>(ws + OFF_CRAW, ws + OFF_NS, ws + OFF_C, ws + OFF_S);
    k_cc<<<nb, t256, 0, stream>>>(ws + OFF_C, ws + OFF_ND, ws + OFF_CC4);
    k_dacc<<<dim3(ESL_D, NCH_D, 20), dim3(1024), 0, stream>>>(edges, ws + OFF_CC4, ws + OFF_DACC);
    k_y_big<<<dim3(NZ, 2, 2), dim3(192), 0, stream>>>(xn, xp, ws + OFF_NS, ws + OFF_DACC, ws + OFF_PART);
    k_y_small<5><<<dim3(16, 8), t256, 0, stream>>>(xs, ws + OFF_NS, ws + OFF_DACC, ws + OFF_YS, 0);
    k_y_small<16><<<dim3(16, 8), t256, 0, stream>>>(xf, ws + OFF_NS, ws + OFF_DACC, ws + OFF_YS, 1);
    k_y_small<21><<<dim3(16, 8), t256, 0, stream>>>(xm, ws + OFF_NS, ws + OFF_DACC, ws + OFF_YS, 2);
    k_red_y<<<dim3(80), dim3(768), 0, stream>>>(ws + OFF_PART, ws + OFF_YS, ws + OFF_Y);
    k_v<<<dim3(20, 4, 8), dim3(128), 0, stream>>>(ws + OFF_Y, W1s, W1f, W1m, W1n, W1p, ws + OFF_V);
    k_m<<<dim3(20), dim3(128), 0, stream>>>(ws + OFF_V, ws + OFF_S, b1, W2, ws + OFF_MP);
    k_out<<<dim3(1), dim3(128), 0, stream>>>(ws + OFF_MP, b2, Wfc, bfc, out);
}